// Round 1
// baseline (385.317 us; speedup 1.0000x reference)
//
#include <hip/hip_runtime.h>
#include <math.h>

#define NQ   12
#define NL   4
#define DIM  4096          // 2^NQ
#define BLK  256
#define APT  (DIM / BLK)   // amplitudes per thread = 16
#define PAIRS (DIM / 2)    // 2048

__global__ __launch_bounds__(BLK) void qsim_kernel(
    const float* __restrict__ x,     // (B, 12)
    const float* __restrict__ qw,    // (144,)
    const float* __restrict__ dw,    // (12, 12)
    const float* __restrict__ db,    // (12,)
    float* __restrict__ out)         // (B, 12)
{
    __shared__ float re[DIM];
    __shared__ float im[DIM];
    __shared__ float g[NL * NQ * 8];   // fused RZ*RY*RX per (layer,qubit): 4 complex entries
    __shared__ float xv[NQ];
    __shared__ float enc_c[NQ], enc_s[NQ];

    const int s   = blockIdx.x;
    const int tid = threadIdx.x;

    // ---- fused variational gate matrices (threads 0..47) ----
    if (tid < NL * NQ) {
        int l = tid / NQ, q = tid % NQ;
        int p = l * 3 * NQ + 3 * q;
        float t1 = qw[p], t2 = qw[p + 1], t3 = qw[p + 2];
        float a, b, c, d, gr, h;
        sincosf(0.5f * t1, &b, &a);   // RX: a=cos, b=sin
        sincosf(0.5f * t2, &d, &c);   // RY: c=cos, d=sin
        sincosf(0.5f * t3, &h, &gr);  // RZ: gr=cos, h=sin
        // M = RY @ RX
        float m00r =  c * a, m00i =  d * b;
        float m01r = -d * a, m01i = -c * b;
        float m10r =  d * a, m10i = -c * b;
        float m11r =  c * a, m11i = -d * b;
        // U = RZ @ M : row0 *= (gr - i h), row1 *= (gr + i h)
        float* G = &g[tid * 8];
        G[0] = gr * m00r + h * m00i;  G[1] = gr * m00i - h * m00r;
        G[2] = gr * m01r + h * m01i;  G[3] = gr * m01i - h * m01r;
        G[4] = gr * m10r - h * m10i;  G[5] = gr * m10i + h * m10r;
        G[6] = gr * m11r - h * m11i;  G[7] = gr * m11i + h * m11r;
    }
    // ---- per-sample encoding angles ----
    if (tid < NQ) xv[tid] = x[s * NQ + tid];
    __syncthreads();
    if (tid < NQ) {
        float ss = 0.f;
        #pragma unroll
        for (int j = 0; j < NQ; ++j) ss += xv[j] * xv[j];
        float inv = rsqrtf(fmaxf(ss, 1e-12f));
        float mx = 0.f;
        #pragma unroll
        for (int j = 0; j < NQ; ++j) mx = fmaxf(mx, fabsf(xv[j] * inv));
        float ang = 3.14159265358979323846f * (xv[tid] * inv) / (mx + 1e-8f);
        float cc, sn;
        sincosf(0.5f * ang, &sn, &cc);
        enc_c[tid] = cc; enc_s[tid] = sn;
    }
    __syncthreads();

    // ---- product-state init: psi = ⊗_w RY(theta_w)|0>  (real) ----
    #pragma unroll
    for (int r = 0; r < APT; ++r) {
        int i = tid + r * BLK;
        float p = 1.f;
        #pragma unroll
        for (int w = 0; w < NQ; ++w) {
            p *= ((i >> (NQ - 1 - w)) & 1) ? enc_s[w] : enc_c[w];
        }
        re[i] = p; im[i] = 0.f;
    }

    // ---- precompute CNOT-ring permutation sigma (same every layer) ----
    // ring: CNOT(c, (c+1)%12) applied c = 0..11 in order; wire w = bit (11-w).
    // final[i] = initial[f_0(f_1(...f_11(i)...))] reversed => iterate c = 11..0.
    int sig[APT];
    #pragma unroll
    for (int r = 0; r < APT; ++r) {
        int j = tid + r * BLK;
        #pragma unroll
        for (int c = NQ - 1; c >= 0; --c) {
            int t = (c + 1) % NQ;
            int cb = (j >> (NQ - 1 - c)) & 1;
            j ^= cb << (NQ - 1 - t);
        }
        sig[r] = j;
    }
    __syncthreads();

    // ---- variational layers ----
    for (int l = 0; l < NL; ++l) {
        for (int q = 0; q < NQ; ++q) {
            const float* G = &g[(l * NQ + q) * 8];
            float u00r = G[0], u00i = G[1], u01r = G[2], u01i = G[3];
            float u10r = G[4], u10i = G[5], u11r = G[6], u11i = G[7];
            int mask = 1 << (NQ - 1 - q);
            #pragma unroll
            for (int k0 = 0; k0 < PAIRS; k0 += BLK) {
                int k   = k0 + tid;
                int low = k & (mask - 1);
                int i0  = ((k - low) << 1) | low;
                int i1  = i0 | mask;
                float a0r = re[i0], a0i = im[i0];
                float a1r = re[i1], a1i = im[i1];
                re[i0] = u00r * a0r - u00i * a0i + u01r * a1r - u01i * a1i;
                im[i0] = u00r * a0i + u00i * a0r + u01r * a1i + u01i * a1r;
                re[i1] = u10r * a0r - u10i * a0i + u11r * a1r - u11i * a1i;
                im[i1] = u10r * a0i + u10i * a0r + u11r * a1i + u11i * a1r;
            }
            __syncthreads();
        }
        // CNOT ring as one permutation: new[i] = old[sigma(i)]
        float tr[APT], ti[APT];
        #pragma unroll
        for (int r = 0; r < APT; ++r) { tr[r] = re[sig[r]]; ti[r] = im[sig[r]]; }
        __syncthreads();
        #pragma unroll
        for (int r = 0; r < APT; ++r) {
            int i = tid + r * BLK;
            re[i] = tr[r]; im[i] = ti[r];
        }
        __syncthreads();
    }

    // ---- Z expectations: q[w] = sum_i (1-2*bit_w(i)) * |psi_i|^2 ----
    float acc[NQ];
    #pragma unroll
    for (int w = 0; w < NQ; ++w) acc[w] = 0.f;
    #pragma unroll
    for (int r = 0; r < APT; ++r) {
        int i = tid + r * BLK;
        float pr = re[i] * re[i] + im[i] * im[i];
        #pragma unroll
        for (int w = 0; w < NQ; ++w) {
            acc[w] += ((i >> (NQ - 1 - w)) & 1) ? -pr : pr;
        }
    }
    __syncthreads();   // done reading psi; reuse re[] as reduction scratch (12*256 <= 4096)
    #pragma unroll
    for (int w = 0; w < NQ; ++w) re[w * BLK + tid] = acc[w];
    __syncthreads();
    for (int st = BLK / 2; st > 0; st >>= 1) {
        if (tid < st) {
            #pragma unroll
            for (int w = 0; w < NQ; ++w) re[w * BLK + tid] += re[w * BLK + tid + st];
        }
        __syncthreads();
    }
    // ---- dense + tanh ----
    if (tid < NQ) {
        float v = db[tid];
        #pragma unroll
        for (int w = 0; w < NQ; ++w) v += re[w * BLK] * dw[w * NQ + tid];
        out[s * NQ + tid] = tanhf(v);
    }
}

extern "C" void kernel_launch(void* const* d_in, const int* in_sizes, int n_in,
                              void* d_out, int out_size, void* d_ws, size_t ws_size,
                              hipStream_t stream) {
    const float* x  = (const float*)d_in[0];
    const float* qw = (const float*)d_in[1];
    const float* dw = (const float*)d_in[2];
    const float* db = (const float*)d_in[3];
    float* out = (float*)d_out;
    int batch = in_sizes[0] / NQ;
    qsim_kernel<<<batch, BLK, 0, stream>>>(x, qw, dw, db, out);
}